// Round 9
// baseline (138.147 us; speedup 1.0000x reference)
//
#include <hip/hip_runtime.h>

// LinearAttentionCell: chunked linear attention, bf16 MFMA.
// R9: coalesced write-path epilogues (LDS transpose tiles -> full-line stores
// for PKt/Vt/Mpre; kills partial-line RMW amplification) + setprio on MFMA.

constexpr int Bn  = 8;
constexpr int Sn  = 2048;
constexpr int Cn  = 512;
constexpr int Tn  = 128;
constexpr int NCn = 16;
constexpr float DKf = 0.04419417382415922f;     // 1/sqrt(512)

typedef __attribute__((ext_vector_type(8))) short bf16x8;
typedef __attribute__((ext_vector_type(4))) float f32x4;

__device__ __forceinline__ unsigned short f2bf(float f) {   // RNE
  unsigned u = __float_as_uint(f);
  u = (u + 0x7fffu + ((u >> 16) & 1u)) >> 16;
  return (unsigned short)u;
}
__device__ __forceinline__ float bf2f(unsigned short h) {
  return __uint_as_float(((unsigned)h) << 16);
}
__device__ __forceinline__ float phi_f(float u) {
  float s = u * DKf;
  return s > 0.0f ? s + 1.0f : __expf(s);       // elu(s)+1
}

// ---- stage a 128x32 bf16 tile global->LDS, swizzle kslot ^= (row>>1)&3 ------
__device__ __forceinline__ void stage128x32(const unsigned short* __restrict__ g,
                                            int ld, unsigned short* lds,
                                            int wid, int lane) {
#pragma unroll
  for (int cc = 0; cc < 2; ++cc) {
    const int row = cc * 64 + wid * 16 + (lane >> 2);
    const int ks  = (lane & 3) ^ ((row >> 1) & 3);
    const unsigned short* src = g + (size_t)row * ld + ks * 8;
    unsigned short* dst = lds + (size_t)(cc * 256 + wid * 64) * 8;  // wave-uniform
    __builtin_amdgcn_global_load_lds(
        (const __attribute__((address_space(1))) void*)src,
        (__attribute__((address_space(3))) void*)dst, 16, 0, 0);
  }
}

// ---- 128x128 out tile, 4 waves (2x2 of 64x64), 3-buffer dist-2 K loop -------
__device__ __forceinline__ void mm_loop(const unsigned short* __restrict__ Ag, int lda,
                                        const unsigned short* __restrict__ Bg, int ldb,
                                        int nkt,
                                        unsigned short* Al, unsigned short* Bl,
                                        f32x4 acc[4][4]) {
  const int t = threadIdx.x, wid = t >> 6, lane = t & 63;
  const int wm = wid >> 1, wn = wid & 1;
  const int fr = lane & 15, kb = lane >> 4;
  stage128x32(Ag, lda, Al, wid, lane);
  stage128x32(Bg, ldb, Bl, wid, lane);
  if (nkt > 1) {
    stage128x32(Ag + 32, lda, Al + 4096, wid, lane);
    stage128x32(Bg + 32, ldb, Bl + 4096, wid, lane);
  }
  int cur = 0;
  for (int kt = 0; kt < nkt; ++kt) {
    if (kt + 2 < nkt) {
      const int nx2 = (cur + 2 >= 3) ? cur - 1 : cur + 2;
      stage128x32(Ag + (kt + 2) * 32, lda, Al + nx2 * 4096, wid, lane);
      stage128x32(Bg + (kt + 2) * 32, ldb, Bl + nx2 * 4096, wid, lane);
      asm volatile("s_waitcnt vmcnt(8)" ::: "memory");
    } else if (kt + 1 < nkt) {
      asm volatile("s_waitcnt vmcnt(4)" ::: "memory");
    } else {
      asm volatile("s_waitcnt vmcnt(0)" ::: "memory");
    }
    __builtin_amdgcn_s_barrier();
    asm volatile("" ::: "memory");          // no ds_read hoist above barrier
    const unsigned short* Ac = Al + cur * 4096;
    const unsigned short* Bc = Bl + cur * 4096;
    bf16x8 af[4], bf[4];
#pragma unroll
    for (int m = 0; m < 4; ++m) {
      const int r = wm * 64 + m * 16 + fr;
      af[m] = *(const bf16x8*)&Ac[r * 32 + ((kb ^ ((r >> 1) & 3)) << 3)];
    }
#pragma unroll
    for (int n = 0; n < 4; ++n) {
      const int r = wn * 64 + n * 16 + fr;
      bf[n] = *(const bf16x8*)&Bc[r * 32 + ((kb ^ ((r >> 1) & 3)) << 3)];
    }
    __builtin_amdgcn_s_setprio(1);
#pragma unroll
    for (int m = 0; m < 4; ++m)
#pragma unroll
      for (int n = 0; n < 4; ++n)
        acc[m][n] = __builtin_amdgcn_mfma_f32_16x16x32_bf16(af[m], bf[n], acc[m][n], 0, 0, 0);
    __builtin_amdgcn_s_setprio(0);
    __builtin_amdgcn_s_barrier();           // all waves done reading cur
    asm volatile("" ::: "memory");
    cur = (cur + 1 >= 3) ? 0 : cur + 1;
  }
}

// ---------------- casts ------------------------------------------------------
__global__ __launch_bounds__(256) void k_cast_x(const float* __restrict__ x,
                                                unsigned short* __restrict__ xb) {
  const size_t i8 = ((size_t)blockIdx.x * 256 + threadIdx.x) * 8;
  float4 a = *(const float4*)&x[i8];
  float4 b = *(const float4*)&x[i8 + 4];
  uint4 o;
  o.x = (unsigned)f2bf(a.x) | ((unsigned)f2bf(a.y) << 16);
  o.y = (unsigned)f2bf(a.z) | ((unsigned)f2bf(a.w) << 16);
  o.z = (unsigned)f2bf(b.x) | ((unsigned)f2bf(b.y) << 16);
  o.w = (unsigned)f2bf(b.z) | ((unsigned)f2bf(b.w) << 16);
  *(uint4*)&xb[i8] = o;
}

__global__ __launch_bounds__(256) void k_cast_w(const float* __restrict__ Wq,
                                                const float* __restrict__ Wk,
                                                const float* __restrict__ Wv,
                                                unsigned short* __restrict__ Wb) {
  const int z = blockIdx.y;
  const float* __restrict__ src = (z == 0) ? Wq : (z == 1 ? Wk : Wv);
  const size_t i8 = ((size_t)blockIdx.x * 256 + threadIdx.x) * 8;
  float4 a = *(const float4*)&src[i8];
  float4 b = *(const float4*)&src[i8 + 4];
  uint4 o;
  o.x = (unsigned)f2bf(a.x) | ((unsigned)f2bf(a.y) << 16);
  o.y = (unsigned)f2bf(a.z) | ((unsigned)f2bf(a.w) << 16);
  o.z = (unsigned)f2bf(b.x) | ((unsigned)f2bf(b.y) << 16);
  o.w = (unsigned)f2bf(b.z) | ((unsigned)f2bf(b.w) << 16);
  *(uint4*)&Wb[(size_t)z * Cn * Cn + i8] = o;
}

// ---------------- K1: projections (bf16 MFMA, XCD-local m-slabs) -------------
// 1536 blocks: xcd = bid&7 owns 16 contiguous m-slabs x 4 n x 3 z.
// z==1 also emits zsum. PKt/Vt written via LDS transpose -> full-line stores.
__global__ __launch_bounds__(256) void k_proj(
    const unsigned short* __restrict__ xb, const unsigned short* __restrict__ Wb,
    unsigned short* __restrict__ PQ, unsigned short* __restrict__ PK,
    unsigned short* __restrict__ PKt, unsigned short* __restrict__ Vt,
    float* __restrict__ zsum)
{
  __shared__ unsigned short smem[2 * 3 * 128 * 32];   // 48 KB: staging / Tt union
  __shared__ float zbuf[2][128];
  unsigned short* Al = smem;
  unsigned short* Bl = smem + 3 * 4096;
  unsigned short* Tt = smem;                          // [128 col][136] post-loop
  const int bid = blockIdx.x;
  const int xcd = bid & 7, idx = bid >> 3;            // idx in 0..191
  const int n = idx & 3, z = (idx >> 2) % 3, mloc = idx / 12;
  const int n0 = n * 128, m0 = (xcd * 16 + mloc) * 128;
  const int t = threadIdx.x, wid = t >> 6, lane = t & 63;
  const int wm = wid >> 1, wn = wid & 1;
  f32x4 acc[4][4];
  const f32x4 zero = {0.f, 0.f, 0.f, 0.f};
#pragma unroll
  for (int m = 0; m < 4; ++m)
#pragma unroll
    for (int nn = 0; nn < 4; ++nn) acc[m][nn] = zero;

  mm_loop(xb + (size_t)m0 * Cn, Cn,
          Wb + (size_t)z * Cn * Cn + (size_t)n0 * Cn, Cn, Cn / 32, Al, Bl, acc);

  float ps[4] = {0.f, 0.f, 0.f, 0.f};
#pragma unroll
  for (int m = 0; m < 4; ++m)
#pragma unroll
    for (int nn = 0; nn < 4; ++nn) {
      const int rl0 = wm * 64 + m * 16 + ((lane >> 4) << 2);   // block-local row
      const int cl  = wn * 64 + nn * 16 + (lane & 15);         // block-local col
      const int row0 = m0 + rl0;
      const int col  = n0 + cl;
      f32x4 v = acc[m][nn];
      if (z == 0) {
#pragma unroll
        for (int j = 0; j < 4; ++j)
          PQ[(size_t)(row0 + j) * Cn + col] = f2bf(phi_f(v[j]));
      } else if (z == 1) {
        ushort4 p;
#pragma unroll
        for (int j = 0; j < 4; ++j) {
          unsigned short u = f2bf(phi_f(v[j]));
          PK[(size_t)(row0 + j) * Cn + col] = u;
          (&p.x)[j] = u;
          ps[nn] += bf2f(u);
        }
        *(ushort4*)&Tt[cl * 136 + rl0] = p;
      } else {
        ushort4 p;
#pragma unroll
        for (int j = 0; j < 4; ++j) (&p.x)[j] = f2bf(v[j]);
        *(ushort4*)&Tt[cl * 136 + rl0] = p;
      }
    }

  if (z == 1) {   // block covers one (b, chunk) x cols n0..n0+127 completely
#pragma unroll
    for (int nn = 0; nn < 4; ++nn) {
      float v = ps[nn];
      v += __shfl_xor(v, 16); v += __shfl_xor(v, 32);   // reduce over kb
      if (lane < 16) zbuf[wm][wn * 64 + nn * 16 + lane] = v;
    }
  }
  if (z >= 1) {
    __syncthreads();                       // Tt (and zbuf) visible to all
    if (z == 1 && t < 128) {
      const int b = m0 >> 11, ch = (m0 >> 7) & 15;
      zsum[((size_t)b * NCn + ch) * Cn + n0 + t] = zbuf[0][t] + zbuf[1][t];
    }
    // coalesced transposed store: thread owns 128 B of one PKt/Vt row
    const int c = t & 127, seg = t >> 7;
    const int bI = m0 >> 11, tq0 = m0 & (Sn - 1);
    unsigned short* dstT = (z == 1 ? PKt : Vt)
                         + ((size_t)bI * Cn + n0 + c) * Sn + tq0 + seg * 64;
    const unsigned short* srcT = &Tt[c * 136 + seg * 64];
#pragma unroll
    for (int i = 0; i < 8; ++i) {
      const int cc = ((i ^ (c & 7)) << 3);         // XOR order: LDS bank spread
      *(uint4*)(dstT + cc) = *(const uint4*)(srcT + cc);
    }
  }
}

// ---------------- K2a: A = tril(PQ_c PK_c^T) bf16; scale fully fused ---------
__global__ __launch_bounds__(256) void k_gram(
    const unsigned short* __restrict__ PQ, const unsigned short* __restrict__ PK,
    const float* __restrict__ zsum,
    unsigned short* __restrict__ Abuf, float* __restrict__ scale)
{
  __shared__ unsigned short Al[3 * 128 * 32], Bl[3 * 128 * 32];
  __shared__ float rsmem[2][128];
  __shared__ float zpl[512];
  const int b = blockIdx.y, ch = blockIdx.x;
  const size_t base = ((size_t)b * Sn + ch * Tn) * Cn;
  f32x4 acc[4][4];
  const f32x4 zero = {0.f, 0.f, 0.f, 0.f};
#pragma unroll
  for (int m = 0; m < 4; ++m)
#pragma unroll
    for (int n = 0; n < 4; ++n) acc[m][n] = zero;

  mm_loop(PQ + base, Cn, PK + base, Cn, Cn / 32, Al, Bl, acc);

  const int t = threadIdx.x, wid = t >> 6, lane = t & 63;
  const int wm = wid >> 1, wn = wid & 1;
  float rsum[4][4];
#pragma unroll
  for (int m = 0; m < 4; ++m)
#pragma unroll
    for (int j = 0; j < 4; ++j) rsum[m][j] = 0.f;
#pragma unroll
  for (int m = 0; m < 4; ++m)
#pragma unroll
    for (int n = 0; n < 4; ++n) {
      f32x4 v = acc[m][n];
#pragma unroll
      for (int j = 0; j < 4; ++j) {
        const int row = wm * 64 + m * 16 + ((lane >> 4) << 2) + j;
        const int col = wn * 64 + n * 16 + (lane & 15);
        unsigned short u = (col <= row) ? f2bf(v[j]) : 0;
        Abuf[((size_t)(b * NCn + ch) * Tn + row) * Tn + col] = u;
        rsum[m][j] += bf2f(u);          // rowsum over the SAME rounded values
      }
    }
#pragma unroll
  for (int m = 0; m < 4; ++m)
#pragma unroll
    for (int j = 0; j < 4; ++j) {
      float r = rsum[m][j];
      r += __shfl_xor(r, 1); r += __shfl_xor(r, 2);
      r += __shfl_xor(r, 4); r += __shfl_xor(r, 8);
      if ((lane & 15) == 0)
        rsmem[wn][wm * 64 + m * 16 + ((lane >> 4) << 2) + j] = r;
    }
  // exclusive chunk-prefix of zsum -> zpl (LDS)
#pragma unroll
  for (int e = 0; e < 2; ++e) {
    const int c = t + e * 256;
    float s = 0.f;
    for (int ch2 = 0; ch2 < ch; ++ch2)
      s += zsum[((size_t)b * NCn + ch2) * Cn + c];
    zpl[c] = s;
  }
  __syncthreads();
  // per-row dot(PQ_row, zpl) + finalize scale (2 threads per row)
  const int row = t >> 1, half = (t & 1) * 256;
  const unsigned short* pq = PQ + base + (size_t)row * Cn + half;
  float dacc = 0.f;
  for (int i = 0; i < 256; i += 8) {
    uint4 q = *(const uint4*)(pq + i);
    dacc += bf2f((unsigned short)(q.x & 0xffff)) * zpl[half + i + 0]
          + bf2f((unsigned short)(q.x >> 16))    * zpl[half + i + 1]
          + bf2f((unsigned short)(q.y & 0xffff)) * zpl[half + i + 2]
          + bf2f((unsigned short)(q.y >> 16))    * zpl[half + i + 3]
          + bf2f((unsigned short)(q.z & 0xffff)) * zpl[half + i + 4]
          + bf2f((unsigned short)(q.z >> 16))    * zpl[half + i + 5]
          + bf2f((unsigned short)(q.w & 0xffff)) * zpl[half + i + 6]
          + bf2f((unsigned short)(q.w >> 16))    * zpl[half + i + 7];
  }
  dacc += __shfl_xor(dacc, 1);
  if ((t & 1) == 0)
    scale[(size_t)b * Sn + ch * Tn + row] =
        rsmem[0][row] + rsmem[1][row] + dacc + 1e-5f;
}

// ---- stage a 64x128 bf16 tile global->LDS, swizzle slot ^= row&7 ------------
__device__ __forceinline__ void stage64x128(const unsigned short* __restrict__ g,
                                            int ld, unsigned short* lds,
                                            int wid, int lane) {
#pragma unroll
  for (int i = 0; i < 4; ++i) {
    const int row = wid * 16 + i * 4 + (lane >> 4);
    const int s   = (lane & 15) ^ (row & 7);
    const unsigned short* src = g + (size_t)row * ld + s * 8;
    unsigned short* dst = lds + (size_t)(wid * 16 + i * 4) * 128;   // wave-uniform
    __builtin_amdgcn_global_load_lds(
        (const __attribute__((address_space(1))) void*)src,
        (__attribute__((address_space(3))) void*)dst, 16, 0, 0);
  }
}

// ---------------- K3a: fused KV + exclusive prefix (BK=128, counted vmcnt) ---
// Mpre written via LDS transpose tile -> full-line coalesced stores.
__global__ __launch_bounds__(256) void k_kvp(
    const unsigned short* __restrict__ PKt, const unsigned short* __restrict__ Vt,
    unsigned short* __restrict__ Mpre)
{
  __shared__ unsigned short smem[2 * 8192 * 2 + 64 * 72];   // Al|Bl|T2
  unsigned short* Al = smem;
  unsigned short* Bl = smem + 2 * 8192;
  unsigned short* T2 = smem + 4 * 8192;                     // [64 d][72]
  const int bid = blockIdx.x;
  const int b = bid & 7, idx = bid >> 3;
  const int d0 = (idx & 7) * 64, c0 = (idx >> 3) * 64;
  const int t = threadIdx.x, wid = t >> 6, lane = t & 63;
  const int wm = wid >> 1, wn = wid & 1;
  const int fr = lane & 15, kb = lane >> 4;
  f32x4 acc[2][2];
  const f32x4 zero = {0.f, 0.f, 0.f, 0.f};
#pragma unroll
  for (int m = 0; m < 2; ++m)
#pragma unroll
    for (int n = 0; n < 2; ++n) acc[m][n] = zero;
  const unsigned short* Ag = PKt + ((size_t)b * Cn + c0) * Sn;
  const unsigned short* Bg = Vt  + ((size_t)b * Cn + d0) * Sn;
  stage64x128(Ag, Sn, Al, wid, lane);
  stage64x128(Bg, Sn, Bl, wid, lane);
  int cur = 0;
  for (int ch = 0; ch < NCn; ++ch) {
    const int nxt = cur ^ 1;
    if (ch + 1 < NCn) {
      stage64x128(Ag + (ch + 1) * Tn, Sn, Al + nxt * 8192, wid, lane);
      stage64x128(Bg + (ch + 1) * Tn, Sn, Bl + nxt * 8192, wid, lane);
      asm volatile("s_waitcnt vmcnt(8)" ::: "memory");
    } else {
      asm volatile("s_waitcnt vmcnt(0)" ::: "memory");
    }
    __builtin_amdgcn_s_barrier();
    asm volatile("" ::: "memory");
    if (ch > 0) {   // Mpre[ch] = sum of chunks < ch (Mpre[0] never read)
#pragma unroll
      for (int m = 0; m < 2; ++m)
#pragma unroll
        for (int n = 0; n < 2; ++n) {
          const int cl = wm * 32 + m * 16 + (kb << 2);
          const int dl = wn * 32 + n * 16 + fr;
          ushort4 p;
#pragma unroll
          for (int j = 0; j < 4; ++j) (&p.x)[j] = f2bf(acc[m][n][j]);
          *(ushort4*)&T2[dl * 72 + cl] = p;
        }
      asm volatile("s_waitcnt lgkmcnt(0)" ::: "memory");
      __builtin_amdgcn_s_barrier();
      asm volatile("" ::: "memory");
      const int r = t & 63, seg = t >> 6;
      const unsigned short* srcT = &T2[r * 72 + seg * 16];
      unsigned short* dstT = Mpre + ((size_t)(b * NCn + ch) * Cn + d0 + r) * Cn
                           + c0 + seg * 16;
      *(uint4*)dstT       = *(const uint4*)srcT;
      *(uint4*)(dstT + 8) = *(const uint4*)(srcT + 8);
    }
    const unsigned short* Ac = Al + cur * 8192;
    const unsigned short* Bc = Bl + cur * 8192;
    __builtin_amdgcn_s_setprio(1);
#pragma unroll
    for (int kt = 0; kt < 4; ++kt) {
      bf16x8 af[2], bf[2];
#pragma unroll
      for (int m = 0; m < 2; ++m) {
        const int r = wm * 32 + m * 16 + fr;
        af[m] = *(const bf16x8*)&Ac[r * 128 + (((kt * 4 + kb) ^ (r & 7)) << 3)];
      }
#pragma unroll
      for (int n = 0; n < 2; ++n) {
        const int r = wn * 32 + n * 16 + fr;
        bf[n] = *(const bf16x8*)&Bc[r * 128 + (((kt * 4 + kb) ^ (r & 7)) << 3)];
      }
#pragma unroll
      for (int m = 0; m < 2; ++m)
#pragma unroll
        for (int n = 0; n < 2; ++n)
          acc[m][n] = __builtin_amdgcn_mfma_f32_16x16x32_bf16(af[m], bf[n], acc[m][n], 0, 0, 0);
    }
    __builtin_amdgcn_s_setprio(0);
    __builtin_amdgcn_s_barrier();
    asm volatile("" ::: "memory");
    cur = nxt;
  }
}

// ---------------- K3b: out = (A@V_c + PQ_c@Mpre_c) / scale (single write) ----
__global__ __launch_bounds__(256) void k_avinter(
    const unsigned short* __restrict__ Abuf, const unsigned short* __restrict__ Vt,
    const unsigned short* __restrict__ PQ, const unsigned short* __restrict__ Mpre,
    const float* __restrict__ scale, float* __restrict__ out)
{
  __shared__ unsigned short Al[3 * 128 * 32], Bl[3 * 128 * 32];
  const int bid = blockIdx.x;
  const int logical = (bid & 7) * 64 + (bid >> 3);
  const int d0 = (logical & 3) * 128;
  const int ch = (logical >> 2) & 15;
  const int b  = logical >> 6;
  const int t0 = ch * Tn;
  f32x4 acc[4][4];
  const f32x4 zero = {0.f, 0.f, 0.f, 0.f};
#pragma unroll
  for (int m = 0; m < 4; ++m)
#pragma unroll
    for (int n = 0; n < 4; ++n) acc[m][n] = zero;

  // intra: A (128x128) @ V_c  (K = 128)
  mm_loop(Abuf + (size_t)(b * NCn + ch) * Tn * Tn, Tn,
          Vt + ((size_t)b * Cn + d0) * Sn + t0, Sn, Tn / 32, Al, Bl, acc);
  // inter: PQ_c @ Mpre_c  (K = 512)
  if (ch > 0)
    mm_loop(PQ + ((size_t)b * Sn + t0) * Cn, Cn,
            Mpre + ((size_t)(b * NCn + ch) * Cn + d0) * Cn, Cn, Cn / 32, Al, Bl, acc);

  const int t = threadIdx.x, wid = t >> 6, lane = t & 63;
  const int wm = wid >> 1, wn = wid & 1;
#pragma unroll
  for (int m = 0; m < 4; ++m)
#pragma unroll
    for (int n = 0; n < 4; ++n) {
      const int row0 = t0 + wm * 64 + m * 16 + ((lane >> 4) << 2);
      const int col  = d0 + wn * 64 + n * 16 + (lane & 15);
      f32x4 v = acc[m][n];
#pragma unroll
      for (int j = 0; j < 4; ++j) {
        const size_t sidx = (size_t)b * Sn + row0 + j;
        out[sidx * Cn + col] = v[j] / scale[sidx];
      }
    }
}

// ---------------- launch -----------------------------------------------------
extern "C" void kernel_launch(void* const* d_in, const int* in_sizes, int n_in,
                              void* d_out, int out_size, void* d_ws, size_t ws_size,
                              hipStream_t stream)
{
  const float* x  = (const float*)d_in[0];
  const float* Wq = (const float*)d_in[1];
  const float* Wk = (const float*)d_in[2];
  const float* Wv = (const float*)d_in[3];
  float* out = (float*)d_out;

  unsigned short* xb   = (unsigned short*)d_ws;
  unsigned short* Wb   = xb   + (size_t)Bn * Sn * Cn;          // 8.39M
  unsigned short* PQ   = Wb   + (size_t)3 * Cn * Cn;           // 0.79M
  unsigned short* PK   = PQ   + (size_t)Bn * Sn * Cn;
  unsigned short* PKt  = PK   + (size_t)Bn * Sn * Cn;
  unsigned short* Vt   = PKt  + (size_t)Bn * Sn * Cn;
  unsigned short* Abuf = Vt   + (size_t)Bn * Sn * Cn;          // 2.10M
  unsigned short* Mpre = Abuf + (size_t)Bn * NCn * Tn * Tn;    // 33.55M
  float* scale = (float*)(Mpre + (size_t)Bn * NCn * Cn * Cn);  // 16K
  float* zsum  = scale + (size_t)Bn * Sn;                      // 64K
  (void)ws_size; (void)in_sizes; (void)n_in; (void)out_size;

  hipLaunchKernelGGL(k_cast_x, dim3(4096), dim3(256), 0, stream, x, xb);
  hipLaunchKernelGGL(k_cast_w, dim3(128, 3), dim3(256), 0, stream, Wq, Wk, Wv, Wb);
  hipLaunchKernelGGL(k_proj, dim3(1536), dim3(256), 0, stream, xb, Wb, PQ, PK, PKt, Vt, zsum);
  hipLaunchKernelGGL(k_gram, dim3(NCn, Bn), dim3(256), 0, stream, PQ, PK, zsum, Abuf, scale);
  hipLaunchKernelGGL(k_kvp, dim3(512), dim3(256), 0, stream, PKt, Vt, Mpre);
  hipLaunchKernelGGL(k_avinter, dim3(512), dim3(256), 0, stream, Abuf, Vt, PQ, Mpre, scale, out);
}